// Round 4
// baseline (355.309 us; speedup 1.0000x reference)
//
#include <hip/hip_runtime.h>
#include <cstdint>
#include <cstddef>

// Problem constants (from reference)
#define XL      432
#define YL      496
#define PLANE   (XL * YL)      // 214272 (y-major: idx = y*XL + x); PLANE % 8 == 0
#define BSZ     4
#define NPIL    80000
#define NPTS    32
#define OUTC    64

__device__ __forceinline__ float bf2f(uint16_t u) { return __uint_as_float(((uint32_t)u) << 16); }
__device__ __forceinline__ uint16_t f2bf(float f) {
    uint32_t x = __float_as_uint(f);
    x += 0x7fffu + ((x >> 16) & 1u);   // RTNE
    return (uint16_t)(x >> 16);
}
__device__ __forceinline__ float ld(const void* p, int i, bool bf) {
    return bf ? bf2f(((const uint16_t*)p)[i]) : ((const float*)p)[i];
}

// In-wave dtype probe on the first 64 words of `pillars`. bf16 data: low half
// as bf16 is a real N(0,1) sample (~64/64 plausible). f32 data: low half is
// mantissa bits -> uniform exponent (~20/64 plausible, sigma 3.7). 40 is >5
// sigma from both. All waves agree; branch is wave-uniform.
__device__ __forceinline__ bool probe_bf16(const void* pillars) {
    const int lane = threadIdx.x & 63;
    uint32_t w = ((const uint32_t*)pillars)[lane];
    float a = fabsf(__uint_as_float(w << 16));
    bool pl = (a > 1e-20f) && (a < 1e4f);
    return __popcll(__ballot(pl)) >= 40;
}

// Kernel 1: one wave per pillar, lane = output channel. BN folded into conv
// weights; 9 affine features collapse to a 4-FMA dot + per-pillar constant.
// pooled stored in the INPUT dtype (bf16 mode: ushort, f32 mode: float).
__global__ __launch_bounds__(256) void pillar_feat_kernel(
    const void* __restrict__ pillars,   // (P, 32, 4) bf16 or f32
    const int*  __restrict__ npoints,   // (P,)
    const int*  __restrict__ coors,     // (P, 4): b, x, y, 0
    const void* __restrict__ conv_w,    // (64, 9)
    const void* __restrict__ gamma,
    const void* __restrict__ beta,
    const void* __restrict__ mean,
    const void* __restrict__ var,
    void*       __restrict__ pooled,    // (P, 64) bf16 or f32, per mode
    int*        __restrict__ map)       // (BSZ, PLANE), pre-filled -1
{
    const bool bf  = probe_bf16(pillars);
    const int lane = threadIdx.x & 63;
    const int wave = threadIdx.x >> 6;
    const int p    = blockIdx.x * 4 + wave;   // 20000 blocks * 4 waves = 80000

    // per-channel constants: fold BN into conv weights
    const float scale  = ld(gamma, lane, bf) * __frsqrt_rn(ld(var, lane, bf) + 1e-3f);
    const float bprime = ld(beta, lane, bf) - ld(mean, lane, bf) * scale;

    float w[9];
    #pragma unroll
    for (int k = 0; k < 9; ++k) w[k] = ld(conv_w, lane * 9 + k, bf) * scale;

    // features affine in raw point (x,y,z,i): 9-dot -> 4-dot + pillar constant
    const float ax = w[0] + w[4] + w[7];
    const float ay = w[1] + w[5] + w[8];
    const float az = w[2] + w[6];
    const float ai = w[3];

    const int np = npoints[p];
    const int cb = coors[p * 4 + 0];
    const int cx = coors[p * 4 + 1];
    const int cy = coors[p * 4 + 2];

    const size_t base = (size_t)p * NPTS;

    // unmasked sum of x,y,z over all 32 points; lanes 0-31 / 32-63 mirror-load,
    // xor-butterfly 1..16 leaves the full sum in every lane.
    float sx, sy, sz;
    if (bf) {
        uint2 d = ((const uint2*)pillars)[base + (lane & 31)];
        sx = __uint_as_float(d.x << 16);
        sy = __uint_as_float(d.x & 0xffff0000u);
        sz = __uint_as_float(d.y << 16);
    } else {
        float4 d = ((const float4*)pillars)[base + (lane & 31)];
        sx = d.x; sy = d.y; sz = d.z;
    }
    #pragma unroll
    for (int m = 1; m <= 16; m <<= 1) {
        sx += __shfl_xor(sx, m, 64);
        sy += __shfl_xor(sy, m, 64);
        sz += __shfl_xor(sz, m, 64);
    }
    const float inv = 1.0f / (float)np;
    const float gx = (float)cx * 0.16f + 0.08f;
    const float gy = (float)cy * 0.16f + (0.08f - 39.68f);
    const float Kc = bprime - inv * (sx * w[4] + sy * w[5] + sz * w[6])
                            - gx * w[7] - gy * w[8];

    // masked rows contribute b' pre-relu; relu(max) == max(relu)
    float m0 = (np < NPTS) ? bprime : -3.0e38f;
    float m1 = -3.0e38f;
    int n = 0;
    if (bf) {
        const uint2* pp = (const uint2*)pillars + base;
        for (; n + 2 <= np; n += 2) {
            uint2 qa = pp[n];
            uint2 qb = pp[n + 1];
            float va = Kc, vb = Kc;
            va = fmaf(__uint_as_float(qa.x << 16),         ax, va);
            va = fmaf(__uint_as_float(qa.x & 0xffff0000u), ay, va);
            va = fmaf(__uint_as_float(qa.y << 16),         az, va);
            va = fmaf(__uint_as_float(qa.y & 0xffff0000u), ai, va);
            vb = fmaf(__uint_as_float(qb.x << 16),         ax, vb);
            vb = fmaf(__uint_as_float(qb.x & 0xffff0000u), ay, vb);
            vb = fmaf(__uint_as_float(qb.y << 16),         az, vb);
            vb = fmaf(__uint_as_float(qb.y & 0xffff0000u), ai, vb);
            m0 = fmaxf(m0, va);
            m1 = fmaxf(m1, vb);
        }
        if (n < np) {
            uint2 qa = pp[n];
            float va = Kc;
            va = fmaf(__uint_as_float(qa.x << 16),         ax, va);
            va = fmaf(__uint_as_float(qa.x & 0xffff0000u), ay, va);
            va = fmaf(__uint_as_float(qa.y << 16),         az, va);
            va = fmaf(__uint_as_float(qa.y & 0xffff0000u), ai, va);
            m0 = fmaxf(m0, va);
        }
    } else {
        const float4* pp = (const float4*)pillars + base;
        for (; n + 2 <= np; n += 2) {
            float4 qa = pp[n];
            float4 qb = pp[n + 1];
            float va = Kc, vb = Kc;
            va = fmaf(qa.x, ax, va); va = fmaf(qa.y, ay, va);
            va = fmaf(qa.z, az, va); va = fmaf(qa.w, ai, va);
            vb = fmaf(qb.x, ax, vb); vb = fmaf(qb.y, ay, vb);
            vb = fmaf(qb.z, az, vb); vb = fmaf(qb.w, ai, vb);
            m0 = fmaxf(m0, va);
            m1 = fmaxf(m1, vb);
        }
        if (n < np) {
            float4 qa = pp[n];
            float va = Kc;
            va = fmaf(qa.x, ax, va); va = fmaf(qa.y, ay, va);
            va = fmaf(qa.z, az, va); va = fmaf(qa.w, ai, va);
            m0 = fmaxf(m0, va);
        }
    }
    float m = fmaxf(fmaxf(m0, m1), 0.0f);

    if (bf) ((uint16_t*)pooled)[(size_t)p * OUTC + lane] = f2bf(m);
    else    ((float*)   pooled)[(size_t)p * OUTC + lane] = m;
    if (lane == 0) map[cb * PLANE + cy * XL + cx] = p;
}

__device__ __forceinline__ uint32_t half16(const uint4& r, int j) {
    uint32_t u = (&r.x)[j >> 1];
    return (j & 1) ? (u >> 16) : (u & 0xffffu);
}

// Kernel 2: stream output (b, c, y, x) in layout order. blockIdx.y = (b, cg):
// cg picks 8 channels. Each thread covers 8 consecutive cells x 8 channels:
// one 16B gather per occupied cell fetches its 8 channels (bf16), then an
// in-register 8x8 transpose feeds 16B coalesced stores per channel plane.
__global__ __launch_bounds__(256) void scatter_canvas_kernel(
    const void* __restrict__ pillars,   // only for dtype probe
    const int*  __restrict__ map,
    const void* __restrict__ pooled,    // bf16 or f32 per mode
    void*       __restrict__ out)
{
    const bool bf = probe_bf16(pillars);
    const int by = blockIdx.y;           // b*8 + cg
    const int b  = by >> 3;
    const int cg = by & 7;               // channels cg*8 .. cg*8+7
    const int e  = (blockIdx.x * 256 + threadIdx.x) * 8;
    if (e >= PLANE) return;              // PLANE % 8 == 0: full groups only

    const int* mp = map + b * PLANE + e;
    int4 ma = ((const int4*)mp)[0];
    int4 mb = ((const int4*)mp)[1];
    const int idx[8] = {ma.x, ma.y, ma.z, ma.w, mb.x, mb.y, mb.z, mb.w};
    const int c0 = cg * 8;

    if (bf) {
        const uint16_t* pb = (const uint16_t*)pooled;
        uint4 row[8];                    // row[i] = 8 bf16 channels of cell i
        #pragma unroll
        for (int i = 0; i < 8; ++i) {
            row[i] = (idx[i] >= 0)
                ? *(const uint4*)(pb + (size_t)idx[i] * OUTC + c0)
                : make_uint4(0u, 0u, 0u, 0u);
        }
        uint16_t* o16 = (uint16_t*)out;
        #pragma unroll
        for (int j = 0; j < 8; ++j) {    // 8x8 bf16 transpose -> 16B stores
            uint4 s;
            s.x = half16(row[0], j) | (half16(row[1], j) << 16);
            s.y = half16(row[2], j) | (half16(row[3], j) << 16);
            s.z = half16(row[4], j) | (half16(row[5], j) << 16);
            s.w = half16(row[6], j) | (half16(row[7], j) << 16);
            *(uint4*)(o16 + (size_t)(b * OUTC + c0 + j) * PLANE + e) = s;
        }
    } else {
        const float* pf = (const float*)pooled;
        float row[8][8];
        #pragma unroll
        for (int i = 0; i < 8; ++i) {
            if (idx[i] >= 0) {
                const float4* r = (const float4*)(pf + (size_t)idx[i] * OUTC + c0);
                float4 lo = r[0], hi = r[1];
                row[i][0] = lo.x; row[i][1] = lo.y; row[i][2] = lo.z; row[i][3] = lo.w;
                row[i][4] = hi.x; row[i][5] = hi.y; row[i][6] = hi.z; row[i][7] = hi.w;
            } else {
                #pragma unroll
                for (int j = 0; j < 8; ++j) row[i][j] = 0.0f;
            }
        }
        float* o32 = (float*)out;
        #pragma unroll
        for (int j = 0; j < 8; ++j) {
            float* dst = o32 + (size_t)(b * OUTC + c0 + j) * PLANE + e;
            *(float4*)(dst)     = make_float4(row[0][j], row[1][j], row[2][j], row[3][j]);
            *(float4*)(dst + 4) = make_float4(row[4][j], row[5][j], row[6][j], row[7][j]);
        }
    }
}

extern "C" void kernel_launch(void* const* d_in, const int* in_sizes, int n_in,
                              void* d_out, int out_size, void* d_ws, size_t ws_size,
                              hipStream_t stream) {
    (void)in_sizes; (void)n_in; (void)out_size; (void)ws_size;

    // ws layout: [map: BSZ*PLANE int = 3.27 MB][pooled: NPIL*64 elems]
    int*  map    = (int*)d_ws;
    void* pooled = (void*)((char*)d_ws + sizeof(int) * (size_t)BSZ * PLANE);

    hipMemsetAsync(map, 0xFF, sizeof(int) * (size_t)BSZ * PLANE, stream);

    pillar_feat_kernel<<<NPIL / 4, 256, 0, stream>>>(
        d_in[0], (const int*)d_in[1], (const int*)d_in[2],
        d_in[3], d_in[4], d_in[5], d_in[6], d_in[7],
        pooled, map);

    dim3 g2((PLANE / 8 + 255) / 256, BSZ * 8);
    scatter_canvas_kernel<<<g2, 256, 0, stream>>>(d_in[0], map, pooled, d_out);
}